// Round 14
// baseline (548.180 us; speedup 1.0000x reference)
//
#include <hip/hip_runtime.h>
#include <hip/hip_cooperative_groups.h>
#include <math.h>

namespace cg = cooperative_groups;

#define N_NODES 100000
#define N_EDGES 1600000
#define IN_DIM 128
#define HID_DIM 64
#define OUT_DIM 40

#define NPAD 102400

#define BUCKET_SHIFT 7
#define BUCKET_NODES 128
#define N_BUCKETS 782          // ceil(100000/128)
#define CHUNK 2048
#define N_CHUNKS 784

#define G1_TILES 1563          // ceil(N_NODES/64)
#define AGG2_TILES 3125        // ceil(N_NODES/32)

typedef _Float16 f16;
typedef _Float16 f16x2 __attribute__((ext_vector_type(2)));
typedef _Float16 f16x4 __attribute__((ext_vector_type(4)));
typedef _Float16 f16x8 __attribute__((ext_vector_type(8)));
typedef float f32x4 __attribute__((ext_vector_type(4)));

#define ZSTR 72

// One cooperative kernel, 8 phases, 7 grid syncs. Phase bodies identical to the
// proven split kernels (R13); persistent blocks with job-stride loops.
// Rationale: ~10.5us launch gap per dispatch measured across rounds -> 9 dispatches
// cost ~95us of gap; one dispatch + 7 grid syncs (~4-6us each) is cheaper.
__global__ __launch_bounds__(256) void gcn_mega_kernel(
    const float* __restrict__ x, const int* __restrict__ ei,
    const float* __restrict__ W1, const float* __restrict__ b1,
    const float* __restrict__ W2, const float* __restrict__ b2,
    float* __restrict__ out, int* __restrict__ wsi)
{
    // ---- workspace layout (derived in-kernel; single source of truth) ----
    int* hist        = wsi;
    int* base        = hist + N_CHUNKS * N_BUCKETS;
    int* bucketTotal = base + N_BUCKETS * N_CHUNKS;
    int* bucketBase  = bucketTotal + 1024;
    int* row_start   = bucketBase + 1024;
    int* cnt         = row_start + NPAD;
    int* csr         = cnt + NPAD;
    int* stage       = csr + N_EDGES;
    float* dinv      = (float*)(stage + N_EDGES);
    f16* h1p         = (f16*)(dinv + NPAD);
    f16* h2p         = h1p + (size_t)N_NODES * HID_DIM;
    f16* w1f         = h2p + (size_t)N_NODES * OUT_DIM;   // 8192 f16
    f16* w2f         = w1f + 8192;                        // 3072 f16
    const int* src = ei;
    const int* dst = ei + N_EDGES;

    cg::grid_group grid = cg::this_grid();
    __shared__ alignas(16) unsigned char smemraw[17408];  // union across phases
    int t = threadIdx.x;
    int G = gridDim.x;

    // ================= P0: per-chunk bucket histogram =================
    {
        int* lh = (int*)smemraw;
        for (int c = blockIdx.x; c < N_CHUNKS; c += G) {
            for (int b = t; b < N_BUCKETS; b += 256) lh[b] = 0;
            __syncthreads();
            int e0 = c * CHUNK;
            for (int i = t; i < CHUNK; i += 256) {
                int e = e0 + i;
                if (e < N_EDGES) atomicAdd(&lh[dst[e] >> BUCKET_SHIFT], 1);
            }
            __syncthreads();
            for (int b = t; b < N_BUCKETS; b += 256) hist[c * N_BUCKETS + b] = lh[b];
            __syncthreads();
        }
    }
    grid.sync();

    // ================= P1: per-bucket exclusive scan over chunks =================
    {
        int* lds = (int*)smemraw;
        for (int b = blockIdx.x; b < N_BUCKETS; b += G) {
            int v[4];
            int s = 0;
            for (int k = 0; k < 4; ++k) {
                int c = 4 * t + k;
                int cv = (c < N_CHUNKS) ? hist[c * N_BUCKETS + b] : 0;
                v[k] = s;
                s += cv;
            }
            lds[t] = s;
            __syncthreads();
            for (int off = 1; off < 256; off <<= 1) {
                int val = (t >= off) ? lds[t - off] : 0;
                __syncthreads();
                lds[t] += val;
                __syncthreads();
            }
            int excl = (t == 0) ? 0 : lds[t - 1];
            for (int k = 0; k < 4; ++k) {
                int c = 4 * t + k;
                if (c < N_CHUNKS) base[b * N_CHUNKS + c] = excl + v[k];
            }
            if (t == 255) bucketTotal[b] = lds[255];
            __syncthreads();
        }
    }
    grid.sync();

    // ================= P2: exclusive scan over bucket totals (block 0) =================
    if (blockIdx.x == 0) {
        int* lds = (int*)smemraw;
        int v[4];
        int s = 0;
        for (int k = 0; k < 4; ++k) {
            int b = 4 * t + k;
            int cv = (b < N_BUCKETS) ? bucketTotal[b] : 0;
            v[k] = s;
            s += cv;
        }
        lds[t] = s;
        __syncthreads();
        for (int off = 1; off < 256; off <<= 1) {
            int val = (t >= off) ? lds[t - off] : 0;
            __syncthreads();
            lds[t] += val;
            __syncthreads();
        }
        int excl = (t == 0) ? 0 : lds[t - 1];
        for (int k = 0; k < 4; ++k) {
            int b = 4 * t + k;
            if (b < N_BUCKETS) bucketBase[b] = excl + v[k];
        }
    }
    grid.sync();

    // ================= P3: scatter edges into bucket-grouped stage =================
    {
        int* lbase = (int*)smemraw;
        int* lcnt  = lbase + N_BUCKETS;
        for (int job = blockIdx.x; job < N_CHUNKS; job += G) {
            int chunk = (job & 7) * 98 + (job >> 3);   // bijection on [0,784)
            for (int b = t; b < N_BUCKETS; b += 256) {
                lbase[b] = base[b * N_CHUNKS + chunk] + bucketBase[b];
                lcnt[b] = 0;
            }
            __syncthreads();
            int e0 = chunk * CHUNK;
            for (int i = t; i < CHUNK; i += 256) {
                int e = e0 + i;
                if (e < N_EDGES) {
                    int d = dst[e];
                    int b = d >> BUCKET_SHIFT;
                    int pos = lbase[b] + atomicAdd(&lcnt[b], 1);
                    stage[pos] = ((d & (BUCKET_NODES - 1)) << 17) | src[e];
                }
            }
            __syncthreads();
        }
    }
    grid.sync();

    // ================= P4: place (csr + row_start/cnt/dinv) + wfrag =================
    {
        int* lhist  = (int*)smemraw;
        int* lscan  = lhist + BUCKET_NODES;
        int* lstart = lscan + BUCKET_NODES;
        int* lcur   = lstart + BUCKET_NODES;
        for (int job = blockIdx.x; job < N_BUCKETS + 2; job += G) {
            if (job < N_BUCKETS) {
                int b = job;
                int est = bucketBase[b];
                int een = (b == N_BUCKETS - 1) ? N_EDGES : bucketBase[b + 1];
                if (t < BUCKET_NODES) { lhist[t] = 0; lcur[t] = 0; }
                __syncthreads();
                for (int e = est + t; e < een; e += 256) atomicAdd(&lhist[stage[e] >> 17], 1);
                __syncthreads();
                if (t < BUCKET_NODES) lscan[t] = lhist[t];
                __syncthreads();
                for (int off = 1; off < BUCKET_NODES; off <<= 1) {
                    int val = (t >= off && t < BUCKET_NODES) ? lscan[t - off] : 0;
                    __syncthreads();
                    if (t < BUCKET_NODES) lscan[t] += val;
                    __syncthreads();
                }
                if (t < BUCKET_NODES) {
                    int myexcl = (t == 0) ? 0 : lscan[t - 1];
                    lstart[t] = est + myexcl;
                    int node = (b << BUCKET_SHIFT) + t;
                    if (node < N_NODES) {
                        row_start[node] = est + myexcl;
                        cnt[node] = lhist[t];
                        dinv[node] = rsqrtf((float)lhist[t] + 1.0f);
                    }
                }
                __syncthreads();
                for (int e = est + t; e < een; e += 256) {
                    int rec = stage[e];
                    int dl = rec >> 17;
                    int pos = lstart[dl] + atomicAdd(&lcur[dl], 1);
                    csr[pos] = rec & 0x1FFFF;
                }
                __syncthreads();
            } else if (job == N_BUCKETS) {
                // wfrag W1 (1024 f16x8 frag-lanes)
                for (int g2 = t; g2 < 1024; g2 += 256) {
                    int f = g2 >> 6, L = g2 & 63;
                    int s = f >> 2, c = f & 3;
                    int q = L >> 4, n = L & 15;
                    f16x8 v;
#pragma unroll
                    for (int j = 0; j < 8; ++j)
                        v[j] = (f16)W1[(32 * s + 8 * q + j) * HID_DIM + 16 * c + n];
                    *(f16x8*)&w1f[(size_t)g2 * 8] = v;
                }
            } else {
                // wfrag W2 (384 f16x8 frag-lanes, cols 40..47 zero-padded)
                for (int g2 = t; g2 < 384; g2 += 256) {
                    int f = g2 >> 6, L = g2 & 63;
                    int s = f / 3, c = f % 3;
                    int q = L >> 4, n = L & 15;
                    int col = 16 * c + n;
                    f16x8 v;
#pragma unroll
                    for (int j = 0; j < 8; ++j)
                        v[j] = (col < OUT_DIM) ? (f16)W2[(32 * s + 8 * q + j) * OUT_DIM + col] : (f16)0.f;
                    *(f16x8*)&w2f[(size_t)g2 * 8] = v;
                }
            }
        }
    }
    grid.sync();

    // ================= P5: gemm1 (MFMA) h1p = f16(dinv * x@W1) =================
    {
        f16* aT = (f16*)smemraw;   // 1088*8 f16 = 17408 B
        int L = t & 63;
        const f16x8* w1f8 = (const f16x8*)w1f;
        f16x8 bfrag[16];
#pragma unroll
        for (int f = 0; f < 16; ++f) bfrag[f] = w1f8[f * 64 + L];

        for (int job = blockIdx.x; job < G1_TILES; job += G) {
            int nodeBase = job * 64;
#pragma unroll
            for (int i = 0; i < 8; ++i) {
                int idx = i * 256 + t;
                int node = idx >> 5;
                int col4 = idx & 31;
                int gnode = nodeBase + node;
                if (gnode >= N_NODES) gnode = N_NODES - 1;
                float4 v = *(const float4*)&x[(size_t)gnode * IN_DIM + col4 * 4];
                int w = node >> 4, m = node & 15;
                int s = col4 >> 3, q = (col4 >> 1) & 3, j0 = (col4 & 1) * 4;
                f16x4 h;
                h.x = (f16)v.x; h.y = (f16)v.y; h.z = (f16)v.z; h.w = (f16)v.w;
                int idx16 = (w * 4 + s) * 68 + 17 * q + m;
                *(f16x4*)&aT[idx16 * 8 + j0] = h;
            }
            __syncthreads();

            int wv = t >> 6;
            int q = L >> 4, m = L & 15;
            f32x4 acc[4] = {};
#pragma unroll
            for (int s = 0; s < 4; ++s) {
                f16x8 afrag = *(const f16x8*)&aT[((wv * 4 + s) * 68 + 17 * q + m) * 8];
#pragma unroll
                for (int c = 0; c < 4; ++c)
                    acc[c] = __builtin_amdgcn_mfma_f32_16x16x32_f16(afrag, bfrag[s * 4 + c], acc[c], 0, 0, 0);
            }
#pragma unroll
            for (int r = 0; r < 4; ++r) {
                int node = nodeBase + 16 * wv + q * 4 + r;
                if (node < N_NODES) {
                    float di = dinv[node];
#pragma unroll
                    for (int c = 0; c < 4; ++c)
                        h1p[(size_t)node * HID_DIM + 16 * c + m] = (f16)(acc[c][r] * di);
                }
            }
            __syncthreads();
        }
    }
    grid.sync();

    // ================= P6: fused agg1 + gemm2 -> h2p =================
    {
        f16* zT = (f16*)smemraw;   // 64*72 f16 = 9216 B
        int wv = t >> 6;
        int L = t & 63;
        int g = L >> 3;       // node group 0..7 within wave
        int s = L & 7;        // f16x8 slot (dims 8s..8s+7)
        const f16x8* h8 = (const f16x8*)h1p;
        float bb[8];
#pragma unroll
        for (int j = 0; j < 8; ++j) bb[j] = b1[8 * s + j];
        const f16x8* w2f8 = (const f16x8*)w2f;

        for (int job = blockIdx.x; job < G1_TILES; job += G) {
            int nodeBase = job * 64;
            for (int p = 0; p < 2; ++p) {
                int nodeLocal = 16 * wv + 8 * p + g;
                int node = nodeBase + nodeLocal;
                float acc[8];
#pragma unroll
                for (int j = 0; j < 8; ++j) acc[j] = 0.f;
                int lim = 0;
                const int* cp = csr;
                bool valid = (node < N_NODES);
                if (valid) {
                    f16x8 sv = h8[(size_t)node * 8 + s];   // self loop
#pragma unroll
                    for (int j = 0; j < 8; ++j) acc[j] = (float)sv[j];
                    lim = cnt[node];
                    cp = csr + row_start[node];
                }
                for (int k = 0; k < lim; k += 4) {
                    int k1 = (k + 1 < lim) ? k + 1 : k;
                    int k2 = (k + 2 < lim) ? k + 2 : k;
                    int k3 = (k + 3 < lim) ? k + 3 : k;
                    int i0 = cp[k], i1 = cp[k1], i2 = cp[k2], i3 = cp[k3];
                    f16x8 f0 = h8[(size_t)i0 * 8 + s];
                    f16x8 f1 = h8[(size_t)i1 * 8 + s];
                    f16x8 f2 = h8[(size_t)i2 * 8 + s];
                    f16x8 f3 = h8[(size_t)i3 * 8 + s];
                    float m1 = (k + 1 < lim) ? 1.f : 0.f;
                    float m2 = (k + 2 < lim) ? 1.f : 0.f;
                    float m3 = (k + 3 < lim) ? 1.f : 0.f;
#pragma unroll
                    for (int j = 0; j < 8; ++j)
                        acc[j] += (float)f0[j] + m1 * (float)f1[j] + m2 * (float)f2[j] + m3 * (float)f3[j];
                }
                f16x8 o;
                if (valid) {
                    float di = dinv[node];
#pragma unroll
                    for (int j = 0; j < 8; ++j) {
                        float v = acc[j] * di + bb[j];
                        o[j] = (f16)(v > 0.f ? v : 0.f);
                    }
                } else {
#pragma unroll
                    for (int j = 0; j < 8; ++j) o[j] = (f16)0.f;
                }
                *(f16x8*)&zT[nodeLocal * ZSTR + 8 * s] = o;
            }
            __syncthreads();

            int q = L >> 4, m = L & 15;
            f32x4 acc2[3] = {};
#pragma unroll
            for (int ks = 0; ks < 2; ++ks) {
                f16x8 afrag = *(const f16x8*)&zT[(16 * wv + m) * ZSTR + 32 * ks + 8 * q];
#pragma unroll
                for (int c = 0; c < 3; ++c)
                    acc2[c] = __builtin_amdgcn_mfma_f32_16x16x32_f16(afrag, w2f8[(ks * 3 + c) * 64 + L], acc2[c], 0, 0, 0);
            }
#pragma unroll
            for (int r = 0; r < 4; ++r) {
                int node = nodeBase + 16 * wv + q * 4 + r;
                if (node < N_NODES) {
                    float di = dinv[node];
                    h2p[(size_t)node * OUT_DIM + m]      = (f16)(acc2[0][r] * di);
                    h2p[(size_t)node * OUT_DIM + 16 + m] = (f16)(acc2[1][r] * di);
                    if (m < 8)
                        h2p[(size_t)node * OUT_DIM + 32 + m] = (f16)(acc2[2][r] * di);
                }
            }
            __syncthreads();
        }
    }
    grid.sync();

    // ================= P7: agg2 -> out =================
    {
        int s = t & 7;                        // f16x8 slot (active s<5)
        const f16x8* h8 = (const f16x8*)h2p;  // row stride 5
        for (int job = blockIdx.x; job < AGG2_TILES; job += G) {
            int node = job * 32 + (t >> 3);
            if (node < N_NODES && s < 5) {
                float acc[8];
                {
                    f16x8 sv = h8[(size_t)node * 5 + s];   // self loop
#pragma unroll
                    for (int j = 0; j < 8; ++j) acc[j] = (float)sv[j];
                }
                int lim = cnt[node];
                const int* cp = csr + row_start[node];
                for (int k = 0; k < lim; k += 4) {
                    int k1 = (k + 1 < lim) ? k + 1 : k;
                    int k2 = (k + 2 < lim) ? k + 2 : k;
                    int k3 = (k + 3 < lim) ? k + 3 : k;
                    int i0 = cp[k], i1 = cp[k1], i2 = cp[k2], i3 = cp[k3];
                    f16x8 f0 = h8[(size_t)i0 * 5 + s];
                    f16x8 f1 = h8[(size_t)i1 * 5 + s];
                    f16x8 f2 = h8[(size_t)i2 * 5 + s];
                    f16x8 f3 = h8[(size_t)i3 * 5 + s];
                    float m1 = (k + 1 < lim) ? 1.f : 0.f;
                    float m2 = (k + 2 < lim) ? 1.f : 0.f;
                    float m3 = (k + 3 < lim) ? 1.f : 0.f;
#pragma unroll
                    for (int j = 0; j < 8; ++j)
                        acc[j] += (float)f0[j] + m1 * (float)f1[j] + m2 * (float)f2[j] + m3 * (float)f3[j];
                }
                float di = dinv[node];
                float4 o0, o1;
                o0.x = acc[0] * di + b2[8 * s + 0];
                o0.y = acc[1] * di + b2[8 * s + 1];
                o0.z = acc[2] * di + b2[8 * s + 2];
                o0.w = acc[3] * di + b2[8 * s + 3];
                o1.x = acc[4] * di + b2[8 * s + 4];
                o1.y = acc[5] * di + b2[8 * s + 5];
                o1.z = acc[6] * di + b2[8 * s + 6];
                o1.w = acc[7] * di + b2[8 * s + 7];
                *(float4*)&out[(size_t)node * OUT_DIM + 8 * s] = o0;
                *(float4*)&out[(size_t)node * OUT_DIM + 8 * s + 4] = o1;
            }
        }
    }
}

extern "C" void kernel_launch(void* const* d_in, const int* in_sizes, int n_in,
                              void* d_out, int out_size, void* d_ws, size_t ws_size,
                              hipStream_t stream) {
    const float* x  = (const float*)d_in[0];
    const int*   ei = (const int*)d_in[1];      // [2, E] int32
    const float* W1 = (const float*)d_in[2];
    const float* b1 = (const float*)d_in[3];
    const float* W2 = (const float*)d_in[4];
    const float* b2 = (const float*)d_in[5];
    float* outp = (float*)d_out;
    int* wsi = (int*)d_ws;

    // co-residency: query occupancy every call (no static caching), grid = blocks/CU * 256 CUs
    int maxb = 0;
    hipOccupancyMaxActiveBlocksPerMultiprocessor(&maxb, gcn_mega_kernel, 256, 0);
    if (maxb < 1) maxb = 1;
    if (maxb > 8) maxb = 8;
    int grid = maxb * 256;

    void* args[] = {(void*)&x, (void*)&ei, (void*)&W1, (void*)&b1,
                    (void*)&W2, (void*)&b2, (void*)&outp, (void*)&wsi};
    hipLaunchCooperativeKernel(gcn_mega_kernel, dim3(grid), dim3(256), args, 0, stream);
}

// Round 15
// 293.896 us; speedup vs baseline: 1.8652x; 1.8652x over previous
//
#include <hip/hip_runtime.h>
#include <math.h>

#define N_NODES 100000
#define N_EDGES 1600000
#define IN_DIM 128
#define HID_DIM 64
#define OUT_DIM 40

#define NPAD 102400

#define BUCKET_SHIFT 7
#define BUCKET_NODES 128
#define N_BUCKETS 782          // ceil(100000/128)
#define CHUNK 2048
#define N_CHUNKS 784           // 8 XCD groups x 98; 784*2048 >= N_EDGES

typedef _Float16 f16;
typedef _Float16 f16x2 __attribute__((ext_vector_type(2)));
typedef _Float16 f16x4 __attribute__((ext_vector_type(4)));
typedef _Float16 f16x8 __attribute__((ext_vector_type(8)));
typedef float f32x4 __attribute__((ext_vector_type(4)));

// -------- workspace layout --------
// ints:  hist[N_CHUNKS*N_BUCKETS] | base[N_BUCKETS*N_CHUNKS] | bucketTotal[1024]
//        (slot [1000] = done-counter) | bucketBase[1024] | row_start[NPAD] |
//        cnt[NPAD] | csr[E] | stage[E]
// floats: dinv[NPAD]
// f16:    h1p[N*64] | h2p[N*40] | w1f[8192] | w2f[3072]
// NO memset needed: every buffer fully written before read each launch
// (done-counter zeroed by hist block 0, stream-ordered before scan_chunks).

#define DONE_SLOT 1000

// 1) per-chunk LDS histogram over dst buckets (jobs 0..783); jobs 784/785 build
//    the MFMA fragment-ordered W1/W2 (independent of edges); job 0 zeroes done.
__global__ __launch_bounds__(256) void hist_kernel(const int* __restrict__ dst,
                                                   int* __restrict__ hist,
                                                   int* __restrict__ bucketTotal,
                                                   const float* __restrict__ W1,
                                                   const float* __restrict__ W2,
                                                   f16* __restrict__ w1f,
                                                   f16* __restrict__ w2f) {
    __shared__ int lh[N_BUCKETS];
    int c = blockIdx.x;
    int t = threadIdx.x;
    if (c == 0 && t == 0) bucketTotal[DONE_SLOT] = 0;
    if (c < N_CHUNKS) {
        for (int b = t; b < N_BUCKETS; b += 256) lh[b] = 0;
        __syncthreads();
        int e0 = c * CHUNK;
        for (int i = t; i < CHUNK; i += 256) {
            int e = e0 + i;
            if (e < N_EDGES) atomicAdd(&lh[dst[e] >> BUCKET_SHIFT], 1);
        }
        __syncthreads();
        for (int b = t; b < N_BUCKETS; b += 256) hist[c * N_BUCKETS + b] = lh[b];
    } else if (c == N_CHUNKS) {
        // wfrag W1: frag f=s*4+cc, lane L holds B[32s+(L>>4)*8+j][16cc+(L&15)]
        for (int g = t; g < 1024; g += 256) {
            int f = g >> 6, L = g & 63;
            int s = f >> 2, cc = f & 3;
            int q = L >> 4, n = L & 15;
            f16x8 v;
#pragma unroll
            for (int j = 0; j < 8; ++j)
                v[j] = (f16)W1[(32 * s + 8 * q + j) * HID_DIM + 16 * cc + n];
            *(f16x8*)&w1f[(size_t)g * 8] = v;
        }
    } else {
        // wfrag W2 (cols 40..47 zero-padded)
        for (int g = t; g < 384; g += 256) {
            int f = g >> 6, L = g & 63;
            int s = f / 3, cc = f % 3;
            int q = L >> 4, n = L & 15;
            int col = 16 * cc + n;
            f16x8 v;
#pragma unroll
            for (int j = 0; j < 8; ++j)
                v[j] = (col < OUT_DIM) ? (f16)W2[(32 * s + 8 * q + j) * OUT_DIM + col] : (f16)0.f;
            *(f16x8*)&w2f[(size_t)g * 8] = v;
        }
    }
}

// 2) per-bucket exclusive scan over chunks -> base[b][c], bucketTotal[b].
//    Last block to finish also scans bucketTotal -> bucketBase (last-block pattern).
__global__ __launch_bounds__(256) void scan_chunks_kernel(const int* __restrict__ hist,
                                                          int* __restrict__ base,
                                                          int* __restrict__ bucketTotal,
                                                          int* __restrict__ bucketBase) {
    __shared__ int lds[256];
    __shared__ int isLast;
    int b = blockIdx.x;
    int t = threadIdx.x;
    int v[4];
    int s = 0;
    for (int k = 0; k < 4; ++k) {
        int c = 4 * t + k;
        int cv = (c < N_CHUNKS) ? hist[c * N_BUCKETS + b] : 0;
        v[k] = s;
        s += cv;
    }
    lds[t] = s;
    __syncthreads();
    for (int off = 1; off < 256; off <<= 1) {
        int val = (t >= off) ? lds[t - off] : 0;
        __syncthreads();
        lds[t] += val;
        __syncthreads();
    }
    int excl = (t == 0) ? 0 : lds[t - 1];
    for (int k = 0; k < 4; ++k) {
        int c = 4 * t + k;
        if (c < N_CHUNKS) base[b * N_CHUNKS + c] = excl + v[k];
    }
    if (t == 255) bucketTotal[b] = lds[255];

    // last-block tail: the final block performs the 782-element bucket scan
    __threadfence();
    __syncthreads();
    if (t == 0) {
        int old = atomicAdd(&bucketTotal[DONE_SLOT], 1);
        isLast = (old == N_BUCKETS - 1);
    }
    __syncthreads();
    if (isLast) {
        __threadfence();   // acquire: bucketTotal writes from all blocks visible
        int v2[4];
        int s2 = 0;
        for (int k = 0; k < 4; ++k) {
            int bb = 4 * t + k;
            int cv = (bb < N_BUCKETS) ? bucketTotal[bb] : 0;
            v2[k] = s2;
            s2 += cv;
        }
        __syncthreads();
        lds[t] = s2;
        __syncthreads();
        for (int off = 1; off < 256; off <<= 1) {
            int val = (t >= off) ? lds[t - off] : 0;
            __syncthreads();
            lds[t] += val;
            __syncthreads();
        }
        int excl2 = (t == 0) ? 0 : lds[t - 1];
        for (int k = 0; k < 4; ++k) {
            int bb = 4 * t + k;
            if (bb < N_BUCKETS) bucketBase[bb] = excl2 + v2[k];
        }
    }
}

// 3) deterministic scatter into bucket-grouped stage; LDS slice counters only.
__global__ __launch_bounds__(256) void scatter_kernel(const int* __restrict__ src,
                                                      const int* __restrict__ dst,
                                                      const int* __restrict__ base,
                                                      const int* __restrict__ bucketBase,
                                                      int* __restrict__ stage) {
    __shared__ int lbase[N_BUCKETS];
    __shared__ int lcnt[N_BUCKETS];
    int bid = blockIdx.x;
    int chunk = (bid & 7) * 98 + (bid >> 3);   // bijection on [0,784)
    int t = threadIdx.x;
    for (int b = t; b < N_BUCKETS; b += 256) {
        lbase[b] = base[b * N_CHUNKS + chunk] + bucketBase[b];
        lcnt[b] = 0;
    }
    __syncthreads();
    int e0 = chunk * CHUNK;
    for (int i = t; i < CHUNK; i += 256) {
        int e = e0 + i;
        if (e < N_EDGES) {
            int d = dst[e];
            int b = d >> BUCKET_SHIFT;
            int pos = lbase[b] + atomicAdd(&lcnt[b], 1);
            stage[pos] = ((d & (BUCKET_NODES - 1)) << 17) | src[e];
        }
    }
}

// 4) one block per bucket: LDS node histogram + scan -> row_start/cnt/dinv + csr place
__global__ __launch_bounds__(256) void place_kernel(const int* __restrict__ stage,
                                                    const int* __restrict__ bucketBase,
                                                    int* __restrict__ csr,
                                                    int* __restrict__ row_start,
                                                    int* __restrict__ cnt,
                                                    float* __restrict__ dinv) {
    __shared__ int lhist[BUCKET_NODES];
    __shared__ int lscan[BUCKET_NODES];
    __shared__ int lstart[BUCKET_NODES];
    __shared__ int lcur[BUCKET_NODES];
    int b = blockIdx.x;
    int t = threadIdx.x;
    int est = bucketBase[b];
    int een = (b == N_BUCKETS - 1) ? N_EDGES : bucketBase[b + 1];
    if (t < BUCKET_NODES) { lhist[t] = 0; lcur[t] = 0; }
    __syncthreads();
    for (int e = est + t; e < een; e += 256) atomicAdd(&lhist[stage[e] >> 17], 1);
    __syncthreads();
    if (t < BUCKET_NODES) lscan[t] = lhist[t];
    __syncthreads();
    for (int off = 1; off < BUCKET_NODES; off <<= 1) {
        int val = (t >= off && t < BUCKET_NODES) ? lscan[t - off] : 0;
        __syncthreads();
        if (t < BUCKET_NODES) lscan[t] += val;
        __syncthreads();
    }
    if (t < BUCKET_NODES) {
        int myexcl = (t == 0) ? 0 : lscan[t - 1];
        lstart[t] = est + myexcl;
        int node = (b << BUCKET_SHIFT) + t;
        if (node < N_NODES) {
            row_start[node] = est + myexcl;
            cnt[node] = lhist[t];
            dinv[node] = rsqrtf((float)lhist[t] + 1.0f);
        }
    }
    __syncthreads();
    for (int e = est + t; e < een; e += 256) {
        int rec = stage[e];
        int dl = rec >> 17;
        int pos = lstart[dl] + atomicAdd(&lcur[dl], 1);
        csr[pos] = rec & 0x1FFFF;
    }
}

// ---------------- gemm1 (MFMA): h1p = f16( dinv * (x @ W1) ) ----------------
__global__ __launch_bounds__(256) void gemm1_kernel(const float* __restrict__ x,
                                                    const f16* __restrict__ w1f,
                                                    const float* __restrict__ dinv,
                                                    f16* __restrict__ h1p) {
    __shared__ f16 aT[1088 * 8];   // 17408 B
    int t = threadIdx.x;
    int nodeBase = blockIdx.x * 64;
    int L = t & 63;

    const f16x8* w1f8 = (const f16x8*)w1f;
    f16x8 bfrag[16];
#pragma unroll
    for (int f = 0; f < 16; ++f) bfrag[f] = w1f8[f * 64 + L];

#pragma unroll
    for (int i = 0; i < 8; ++i) {
        int idx = i * 256 + t;
        int node = idx >> 5;
        int col4 = idx & 31;
        int gnode = nodeBase + node;
        if (gnode >= N_NODES) gnode = N_NODES - 1;
        float4 v = *(const float4*)&x[(size_t)gnode * IN_DIM + col4 * 4];
        int w = node >> 4, m = node & 15;
        int s = col4 >> 3, q = (col4 >> 1) & 3, j0 = (col4 & 1) * 4;
        f16x4 h;
        h.x = (f16)v.x; h.y = (f16)v.y; h.z = (f16)v.z; h.w = (f16)v.w;
        int idx16 = (w * 4 + s) * 68 + 17 * q + m;
        *(f16x4*)&aT[idx16 * 8 + j0] = h;
    }
    __syncthreads();

    int wv = t >> 6;
    int q = L >> 4, m = L & 15;
    f32x4 acc[4] = {};
#pragma unroll
    for (int s = 0; s < 4; ++s) {
        f16x8 afrag = *(const f16x8*)&aT[((wv * 4 + s) * 68 + 17 * q + m) * 8];
#pragma unroll
        for (int c = 0; c < 4; ++c)
            acc[c] = __builtin_amdgcn_mfma_f32_16x16x32_f16(afrag, bfrag[s * 4 + c], acc[c], 0, 0, 0);
    }

#pragma unroll
    for (int r = 0; r < 4; ++r) {
        int node = nodeBase + 16 * wv + q * 4 + r;
        if (node < N_NODES) {
            float di = dinv[node];
#pragma unroll
            for (int c = 0; c < 4; ++c)
                h1p[(size_t)node * HID_DIM + 16 * c + m] = (f16)(acc[c][r] * di);
        }
    }
}

// ---------------- fused agg1 + gemm2 ----------------
// Phase 1: 8 nodes per wave concurrently (8-lane groups, lane reads f16x8=16B;
// one group = one 128B row) -> 32 rows in flight per wave with unroll-4, masked tail.
// Phase 2: MFMA z @ W2 (cols zero-padded to 48) -> h2p.
#define ZSTR 72
__global__ __launch_bounds__(256) void agg1mm_kernel(const f16* __restrict__ h1p,
                                                     const int* __restrict__ csr,
                                                     const int* __restrict__ row_start,
                                                     const int* __restrict__ cnt,
                                                     const float* __restrict__ dinv,
                                                     const float* __restrict__ b1,
                                                     const f16* __restrict__ w2f,
                                                     f16* __restrict__ h2p) {
    __shared__ f16 zT[64 * ZSTR];   // 9216 B
    int t = threadIdx.x;
    int nodeBase = blockIdx.x * 64;
    int wv = t >> 6;
    int L = t & 63;
    int g = L >> 3;       // node group 0..7 within wave
    int s = L & 7;        // sublane: f16x8 slot (dims 8s..8s+7)
    const f16x8* h8 = (const f16x8*)h1p;   // row stride 8 (f16x8 units)
    float bb[8];
#pragma unroll
    for (int j = 0; j < 8; ++j) bb[j] = b1[8 * s + j];

    for (int p = 0; p < 2; ++p) {
        int nodeLocal = 16 * wv + 8 * p + g;
        int node = nodeBase + nodeLocal;
        float acc[8];
#pragma unroll
        for (int j = 0; j < 8; ++j) acc[j] = 0.f;
        int lim = 0;
        const int* cp = csr;
        bool valid = (node < N_NODES);
        if (valid) {
            f16x8 sv = h8[(size_t)node * 8 + s];   // self loop
#pragma unroll
            for (int j = 0; j < 8; ++j) acc[j] = (float)sv[j];
            lim = cnt[node];
            cp = csr + row_start[node];
        }
        for (int k = 0; k < lim; k += 4) {
            int k1 = (k + 1 < lim) ? k + 1 : k;
            int k2 = (k + 2 < lim) ? k + 2 : k;
            int k3 = (k + 3 < lim) ? k + 3 : k;
            int i0 = cp[k], i1 = cp[k1], i2 = cp[k2], i3 = cp[k3];
            f16x8 f0 = h8[(size_t)i0 * 8 + s];
            f16x8 f1 = h8[(size_t)i1 * 8 + s];
            f16x8 f2 = h8[(size_t)i2 * 8 + s];
            f16x8 f3 = h8[(size_t)i3 * 8 + s];
            float m1 = (k + 1 < lim) ? 1.f : 0.f;
            float m2 = (k + 2 < lim) ? 1.f : 0.f;
            float m3 = (k + 3 < lim) ? 1.f : 0.f;
#pragma unroll
            for (int j = 0; j < 8; ++j)
                acc[j] += (float)f0[j] + m1 * (float)f1[j] + m2 * (float)f2[j] + m3 * (float)f3[j];
        }
        f16x8 o;
        if (valid) {
            float di = dinv[node];
#pragma unroll
            for (int j = 0; j < 8; ++j) {
                float v = acc[j] * di + bb[j];
                o[j] = (f16)(v > 0.f ? v : 0.f);
            }
        } else {
#pragma unroll
            for (int j = 0; j < 8; ++j) o[j] = (f16)0.f;
        }
        *(f16x8*)&zT[nodeLocal * ZSTR + 8 * s] = o;
    }
    __syncthreads();

    // Phase 2: wave wv -> m-tile wv (nodes nodeBase+16*wv .. +15)
    int q = L >> 4, m = L & 15;
    const f16x8* w2f8 = (const f16x8*)w2f;
    f32x4 acc2[3] = {};
#pragma unroll
    for (int ks = 0; ks < 2; ++ks) {
        f16x8 afrag = *(const f16x8*)&zT[(16 * wv + m) * ZSTR + 32 * ks + 8 * q];
#pragma unroll
        for (int c = 0; c < 3; ++c)
            acc2[c] = __builtin_amdgcn_mfma_f32_16x16x32_f16(afrag, w2f8[(ks * 3 + c) * 64 + L], acc2[c], 0, 0, 0);
    }
#pragma unroll
    for (int r = 0; r < 4; ++r) {
        int node = nodeBase + 16 * wv + q * 4 + r;
        if (node < N_NODES) {
            float di = dinv[node];
            h2p[(size_t)node * OUT_DIM + m]      = (f16)(acc2[0][r] * di);
            h2p[(size_t)node * OUT_DIM + 16 + m] = (f16)(acc2[1][r] * di);
            if (m < 8)
                h2p[(size_t)node * OUT_DIM + 32 + m] = (f16)(acc2[2][r] * di);
        }
    }
}

// agg2: 1 node per 8-lane group (lanes s<5 carry the 80B row as f16x8),
// 32 groups per block; unroll-4 with masked tail -> 32 rows in flight per wave.
__global__ __launch_bounds__(256) void agg2_kernel(const f16* __restrict__ h2p,
                                                   const int* __restrict__ csr,
                                                   const int* __restrict__ row_start,
                                                   const int* __restrict__ cnt,
                                                   const float* __restrict__ dinv,
                                                   const float* __restrict__ b2,
                                                   float* __restrict__ out) {
    int t = threadIdx.x;
    int node = blockIdx.x * 32 + (t >> 3);
    int s = t & 7;                        // f16x8 slot: dims 8s..8s+7 (active s<5)
    if (node >= N_NODES || s >= 5) return;
    const f16x8* h8 = (const f16x8*)h2p;  // row stride 5 (f16x8 units)
    float acc[8];
    {
        f16x8 sv = h8[(size_t)node * 5 + s];   // self loop
#pragma unroll
        for (int j = 0; j < 8; ++j) acc[j] = (float)sv[j];
    }
    int lim = cnt[node];
    const int* cp = csr + row_start[node];
    for (int k = 0; k < lim; k += 4) {
        int k1 = (k + 1 < lim) ? k + 1 : k;
        int k2 = (k + 2 < lim) ? k + 2 : k;
        int k3 = (k + 3 < lim) ? k + 3 : k;
        int i0 = cp[k], i1 = cp[k1], i2 = cp[k2], i3 = cp[k3];
        f16x8 f0 = h8[(size_t)i0 * 5 + s];
        f16x8 f1 = h8[(size_t)i1 * 5 + s];
        f16x8 f2 = h8[(size_t)i2 * 5 + s];
        f16x8 f3 = h8[(size_t)i3 * 5 + s];
        float m1 = (k + 1 < lim) ? 1.f : 0.f;
        float m2 = (k + 2 < lim) ? 1.f : 0.f;
        float m3 = (k + 3 < lim) ? 1.f : 0.f;
#pragma unroll
        for (int j = 0; j < 8; ++j)
            acc[j] += (float)f0[j] + m1 * (float)f1[j] + m2 * (float)f2[j] + m3 * (float)f3[j];
    }
    float di = dinv[node];
    float4 o0, o1;
    o0.x = acc[0] * di + b2[8 * s + 0];
    o0.y = acc[1] * di + b2[8 * s + 1];
    o0.z = acc[2] * di + b2[8 * s + 2];
    o0.w = acc[3] * di + b2[8 * s + 3];
    o1.x = acc[4] * di + b2[8 * s + 4];
    o1.y = acc[5] * di + b2[8 * s + 5];
    o1.z = acc[6] * di + b2[8 * s + 6];
    o1.w = acc[7] * di + b2[8 * s + 7];
    *(float4*)&out[(size_t)node * OUT_DIM + 8 * s] = o0;
    *(float4*)&out[(size_t)node * OUT_DIM + 8 * s + 4] = o1;
}

extern "C" void kernel_launch(void* const* d_in, const int* in_sizes, int n_in,
                              void* d_out, int out_size, void* d_ws, size_t ws_size,
                              hipStream_t stream) {
    const float* x  = (const float*)d_in[0];
    const int*   ei = (const int*)d_in[1];      // [2, E] int32
    const float* W1 = (const float*)d_in[2];
    const float* b1 = (const float*)d_in[3];
    const float* W2 = (const float*)d_in[4];
    const float* b2 = (const float*)d_in[5];
    float* out = (float*)d_out;

    const int* src = ei;
    const int* dst = ei + N_EDGES;

    int* wsi        = (int*)d_ws;
    int* hist       = wsi;
    int* base       = hist + N_CHUNKS * N_BUCKETS;
    int* bucketTotal= base + N_BUCKETS * N_CHUNKS;
    int* bucketBase = bucketTotal + 1024;
    int* row_start  = bucketBase + 1024;
    int* cnt        = row_start + NPAD;
    int* csr        = cnt + NPAD;
    int* stage      = csr + N_EDGES;
    float* dinv     = (float*)(stage + N_EDGES);
    f16*   h1p      = (f16*)(dinv + NPAD);
    f16*   h2p      = h1p + (size_t)N_NODES * HID_DIM;
    f16*   w1f      = h2p + (size_t)N_NODES * OUT_DIM;   // 8192 f16
    f16*   w2f      = w1f + 8192;                        // 3072 f16

    // D1: hist (+ wfrag jobs + done-counter zero)
    hist_kernel<<<N_CHUNKS + 2, 256, 0, stream>>>(dst, hist, bucketTotal, W1, W2, w1f, w2f);
    // D2: chunk scans (+ last-block bucket scan -> bucketBase)
    scan_chunks_kernel<<<N_BUCKETS, 256, 0, stream>>>(hist, base, bucketTotal, bucketBase);
    // D3: scatter into bucket-grouped stage
    scatter_kernel<<<N_CHUNKS, 256, 0, stream>>>(src, dst, base, bucketBase, stage);
    // D4: place -> csr/row_start/cnt/dinv
    place_kernel<<<N_BUCKETS, 256, 0, stream>>>(stage, bucketBase, csr, row_start, cnt, dinv);
    // D5-D7: gemm1 -> fused agg1+gemm2 -> agg2
    gemm1_kernel<<<(N_NODES + 63) / 64, 256, 0, stream>>>(x, w1f, dinv, h1p);
    agg1mm_kernel<<<(N_NODES + 63) / 64, 256, 0, stream>>>(h1p, csr, row_start, cnt, dinv, b1, w2f, h2p);
    agg2_kernel<<<(N_NODES + 31) / 32, 256, 0, stream>>>(h2p, csr, row_start, cnt, dinv, b2, out);
}

// Round 16
// 215.744 us; speedup vs baseline: 2.5409x; 1.3622x over previous
//
#include <hip/hip_runtime.h>
#include <math.h>

#define N_NODES 100000
#define N_EDGES 1600000
#define IN_DIM 128
#define HID_DIM 64
#define OUT_DIM 40

#define NPAD 102400

#define BUCKET_SHIFT 7
#define BUCKET_NODES 128
#define N_BUCKETS 782          // ceil(100000/128)
#define CHUNK 2048
#define N_CHUNKS 784           // 8 XCD groups x 98; 784*2048 >= N_EDGES

typedef _Float16 f16;
typedef _Float16 f16x2 __attribute__((ext_vector_type(2)));
typedef _Float16 f16x4 __attribute__((ext_vector_type(4)));
typedef _Float16 f16x8 __attribute__((ext_vector_type(8)));
typedef float f32x4 __attribute__((ext_vector_type(4)));

// -------- workspace layout --------
// ints:  hist[N_BUCKETS*N_CHUNKS] (TRANSPOSED: hist[b][c]) | base[N_BUCKETS*N_CHUNKS] |
//        bucketTotal[1024] | bucketBase[1024] | row_start[NPAD] | cnt[NPAD] | csr[E] | stage[E]
// floats: dinv[NPAD]
// f16:    h1p[N*64] | h2p[N*40] | w1f[8192] | w2f[3072]
// NO memset needed: every buffer fully written before read each launch.

// 1) per-chunk LDS histogram over dst buckets (jobs 0..783); jobs 784/785 build
//    the MFMA fragment-ordered W1/W2. hist stored transposed (hist[b][c]) so the
//    scan reads coalesced rows; the scattered 4B writes here are L2-absorbed
//    (2.45 MB working set, fire-and-forget).
__global__ __launch_bounds__(256) void hist_kernel(const int* __restrict__ dst,
                                                   int* __restrict__ hist,
                                                   const float* __restrict__ W1,
                                                   const float* __restrict__ W2,
                                                   f16* __restrict__ w1f,
                                                   f16* __restrict__ w2f) {
    __shared__ int lh[N_BUCKETS];
    int c = blockIdx.x;
    int t = threadIdx.x;
    if (c < N_CHUNKS) {
        for (int b = t; b < N_BUCKETS; b += 256) lh[b] = 0;
        __syncthreads();
        int e0 = c * CHUNK;
        for (int i = t; i < CHUNK; i += 256) {
            int e = e0 + i;
            if (e < N_EDGES) atomicAdd(&lh[dst[e] >> BUCKET_SHIFT], 1);
        }
        __syncthreads();
        for (int b = t; b < N_BUCKETS; b += 256) hist[b * N_CHUNKS + c] = lh[b];
    } else if (c == N_CHUNKS) {
        // wfrag W1: frag f=s*4+cc, lane L holds B[32s+(L>>4)*8+j][16cc+(L&15)]
        for (int g = t; g < 1024; g += 256) {
            int f = g >> 6, L = g & 63;
            int s = f >> 2, cc = f & 3;
            int q = L >> 4, n = L & 15;
            f16x8 v;
#pragma unroll
            for (int j = 0; j < 8; ++j)
                v[j] = (f16)W1[(32 * s + 8 * q + j) * HID_DIM + 16 * cc + n];
            *(f16x8*)&w1f[(size_t)g * 8] = v;
        }
    } else {
        // wfrag W2 (cols 40..47 zero-padded)
        for (int g = t; g < 384; g += 256) {
            int f = g >> 6, L = g & 63;
            int s = f / 3, cc = f % 3;
            int q = L >> 4, n = L & 15;
            int col = 16 * cc + n;
            f16x8 v;
#pragma unroll
            for (int j = 0; j < 8; ++j)
                v[j] = (col < OUT_DIM) ? (f16)W2[(32 * s + 8 * q + j) * OUT_DIM + col] : (f16)0.f;
            *(f16x8*)&w2f[(size_t)g * 8] = v;
        }
    }
}

// 2) per-bucket exclusive scan over chunks -> base[b][c], bucketTotal[b].
//    hist transposed -> fully coalesced row reads.
__global__ __launch_bounds__(256) void scan_chunks_kernel(const int* __restrict__ hist,
                                                          int* __restrict__ base,
                                                          int* __restrict__ bucketTotal) {
    __shared__ int lds[256];
    int b = blockIdx.x;
    int t = threadIdx.x;
    int v[4];
    int s = 0;
    for (int k = 0; k < 4; ++k) {
        int c = 4 * t + k;
        int cv = (c < N_CHUNKS) ? hist[b * N_CHUNKS + c] : 0;
        v[k] = s;
        s += cv;
    }
    lds[t] = s;
    __syncthreads();
    for (int off = 1; off < 256; off <<= 1) {
        int val = (t >= off) ? lds[t - off] : 0;
        __syncthreads();
        lds[t] += val;
        __syncthreads();
    }
    int excl = (t == 0) ? 0 : lds[t - 1];
    for (int k = 0; k < 4; ++k) {
        int c = 4 * t + k;
        if (c < N_CHUNKS) base[b * N_CHUNKS + c] = excl + v[k];
    }
    if (t == 255) bucketTotal[b] = lds[255];
}

// 3) exclusive scan over 782 bucket totals -> bucketBase
__global__ __launch_bounds__(256) void scan_buckets_kernel(const int* __restrict__ bucketTotal,
                                                           int* __restrict__ bucketBase) {
    __shared__ int lds[256];
    int t = threadIdx.x;
    int v[4];
    int s = 0;
    for (int k = 0; k < 4; ++k) {
        int b = 4 * t + k;
        int cv = (b < N_BUCKETS) ? bucketTotal[b] : 0;
        v[k] = s;
        s += cv;
    }
    lds[t] = s;
    __syncthreads();
    for (int off = 1; off < 256; off <<= 1) {
        int val = (t >= off) ? lds[t - off] : 0;
        __syncthreads();
        lds[t] += val;
        __syncthreads();
    }
    int excl = (t == 0) ? 0 : lds[t - 1];
    for (int k = 0; k < 4; ++k) {
        int b = 4 * t + k;
        if (b < N_BUCKETS) bucketBase[b] = excl + v[k];
    }
}

// 4) deterministic scatter into bucket-grouped stage; LDS slice counters only.
__global__ __launch_bounds__(256) void scatter_kernel(const int* __restrict__ src,
                                                      const int* __restrict__ dst,
                                                      const int* __restrict__ base,
                                                      const int* __restrict__ bucketBase,
                                                      int* __restrict__ stage) {
    __shared__ int lbase[N_BUCKETS];
    __shared__ int lcnt[N_BUCKETS];
    int bid = blockIdx.x;
    int chunk = (bid & 7) * 98 + (bid >> 3);   // bijection on [0,784)
    int t = threadIdx.x;
    for (int b = t; b < N_BUCKETS; b += 256) {
        lbase[b] = base[b * N_CHUNKS + chunk] + bucketBase[b];
        lcnt[b] = 0;
    }
    __syncthreads();
    int e0 = chunk * CHUNK;
    for (int i = t; i < CHUNK; i += 256) {
        int e = e0 + i;
        if (e < N_EDGES) {
            int d = dst[e];
            int b = d >> BUCKET_SHIFT;
            int pos = lbase[b] + atomicAdd(&lcnt[b], 1);
            stage[pos] = ((d & (BUCKET_NODES - 1)) << 17) | src[e];
        }
    }
}

// 5) one block per bucket: LDS node histogram + scan -> row_start/cnt/dinv + csr place
__global__ __launch_bounds__(256) void place_kernel(const int* __restrict__ stage,
                                                    const int* __restrict__ bucketBase,
                                                    int* __restrict__ csr,
                                                    int* __restrict__ row_start,
                                                    int* __restrict__ cnt,
                                                    float* __restrict__ dinv) {
    __shared__ int lhist[BUCKET_NODES];
    __shared__ int lscan[BUCKET_NODES];
    __shared__ int lstart[BUCKET_NODES];
    __shared__ int lcur[BUCKET_NODES];
    int b = blockIdx.x;
    int t = threadIdx.x;
    int est = bucketBase[b];
    int een = (b == N_BUCKETS - 1) ? N_EDGES : bucketBase[b + 1];
    if (t < BUCKET_NODES) { lhist[t] = 0; lcur[t] = 0; }
    __syncthreads();
    for (int e = est + t; e < een; e += 256) atomicAdd(&lhist[stage[e] >> 17], 1);
    __syncthreads();
    if (t < BUCKET_NODES) lscan[t] = lhist[t];
    __syncthreads();
    for (int off = 1; off < BUCKET_NODES; off <<= 1) {
        int val = (t >= off && t < BUCKET_NODES) ? lscan[t - off] : 0;
        __syncthreads();
        if (t < BUCKET_NODES) lscan[t] += val;
        __syncthreads();
    }
    if (t < BUCKET_NODES) {
        int myexcl = (t == 0) ? 0 : lscan[t - 1];
        lstart[t] = est + myexcl;
        int node = (b << BUCKET_SHIFT) + t;
        if (node < N_NODES) {
            row_start[node] = est + myexcl;
            cnt[node] = lhist[t];
            dinv[node] = rsqrtf((float)lhist[t] + 1.0f);
        }
    }
    __syncthreads();
    for (int e = est + t; e < een; e += 256) {
        int rec = stage[e];
        int dl = rec >> 17;
        int pos = lstart[dl] + atomicAdd(&lcur[dl], 1);
        csr[pos] = rec & 0x1FFFF;
    }
}

// ---------------- gemm1 (MFMA): h1p = f16( dinv * (x @ W1) ) ----------------
__global__ __launch_bounds__(256) void gemm1_kernel(const float* __restrict__ x,
                                                    const f16* __restrict__ w1f,
                                                    const float* __restrict__ dinv,
                                                    f16* __restrict__ h1p) {
    __shared__ f16 aT[1088 * 8];   // 17408 B
    int t = threadIdx.x;
    int nodeBase = blockIdx.x * 64;
    int L = t & 63;

    const f16x8* w1f8 = (const f16x8*)w1f;
    f16x8 bfrag[16];
#pragma unroll
    for (int f = 0; f < 16; ++f) bfrag[f] = w1f8[f * 64 + L];

#pragma unroll
    for (int i = 0; i < 8; ++i) {
        int idx = i * 256 + t;
        int node = idx >> 5;
        int col4 = idx & 31;
        int gnode = nodeBase + node;
        if (gnode >= N_NODES) gnode = N_NODES - 1;
        float4 v = *(const float4*)&x[(size_t)gnode * IN_DIM + col4 * 4];
        int w = node >> 4, m = node & 15;
        int s = col4 >> 3, q = (col4 >> 1) & 3, j0 = (col4 & 1) * 4;
        f16x4 h;
        h.x = (f16)v.x; h.y = (f16)v.y; h.z = (f16)v.z; h.w = (f16)v.w;
        int idx16 = (w * 4 + s) * 68 + 17 * q + m;
        *(f16x4*)&aT[idx16 * 8 + j0] = h;
    }
    __syncthreads();

    int wv = t >> 6;
    int q = L >> 4, m = L & 15;
    f32x4 acc[4] = {};
#pragma unroll
    for (int s = 0; s < 4; ++s) {
        f16x8 afrag = *(const f16x8*)&aT[((wv * 4 + s) * 68 + 17 * q + m) * 8];
#pragma unroll
        for (int c = 0; c < 4; ++c)
            acc[c] = __builtin_amdgcn_mfma_f32_16x16x32_f16(afrag, bfrag[s * 4 + c], acc[c], 0, 0, 0);
    }

#pragma unroll
    for (int r = 0; r < 4; ++r) {
        int node = nodeBase + 16 * wv + q * 4 + r;
        if (node < N_NODES) {
            float di = dinv[node];
#pragma unroll
            for (int c = 0; c < 4; ++c)
                h1p[(size_t)node * HID_DIM + 16 * c + m] = (f16)(acc[c][r] * di);
        }
    }
}

// ---------------- fused agg1 + gemm2 ----------------
// Phase 1: 8 nodes per wave concurrently (8-lane groups, lane reads f16x8=16B;
// one group = one 128B row) -> 32 rows in flight per wave with unroll-4, masked tail.
// Phase 2: MFMA z @ W2 (cols zero-padded to 48) -> h2p.
#define ZSTR 72
__global__ __launch_bounds__(256) void agg1mm_kernel(const f16* __restrict__ h1p,
                                                     const int* __restrict__ csr,
                                                     const int* __restrict__ row_start,
                                                     const int* __restrict__ cnt,
                                                     const float* __restrict__ dinv,
                                                     const float* __restrict__ b1,
                                                     const f16* __restrict__ w2f,
                                                     f16* __restrict__ h2p) {
    __shared__ f16 zT[64 * ZSTR];   // 9216 B
    int t = threadIdx.x;
    int nodeBase = blockIdx.x * 64;
    int wv = t >> 6;
    int L = t & 63;
    int g = L >> 3;       // node group 0..7 within wave
    int s = L & 7;        // sublane: f16x8 slot (dims 8s..8s+7)
    const f16x8* h8 = (const f16x8*)h1p;   // row stride 8 (f16x8 units)
    float bb[8];
#pragma unroll
    for (int j = 0; j < 8; ++j) bb[j] = b1[8 * s + j];

    for (int p = 0; p < 2; ++p) {
        int nodeLocal = 16 * wv + 8 * p + g;
        int node = nodeBase + nodeLocal;
        float acc[8];
#pragma unroll
        for (int j = 0; j < 8; ++j) acc[j] = 0.f;
        int lim = 0;
        const int* cp = csr;
        bool valid = (node < N_NODES);
        if (valid) {
            f16x8 sv = h8[(size_t)node * 8 + s];   // self loop
#pragma unroll
            for (int j = 0; j < 8; ++j) acc[j] = (float)sv[j];
            lim = cnt[node];
            cp = csr + row_start[node];
        }
        for (int k = 0; k < lim; k += 4) {
            int k1 = (k + 1 < lim) ? k + 1 : k;
            int k2 = (k + 2 < lim) ? k + 2 : k;
            int k3 = (k + 3 < lim) ? k + 3 : k;
            int i0 = cp[k], i1 = cp[k1], i2 = cp[k2], i3 = cp[k3];
            f16x8 f0 = h8[(size_t)i0 * 8 + s];
            f16x8 f1 = h8[(size_t)i1 * 8 + s];
            f16x8 f2 = h8[(size_t)i2 * 8 + s];
            f16x8 f3 = h8[(size_t)i3 * 8 + s];
            float m1 = (k + 1 < lim) ? 1.f : 0.f;
            float m2 = (k + 2 < lim) ? 1.f : 0.f;
            float m3 = (k + 3 < lim) ? 1.f : 0.f;
#pragma unroll
            for (int j = 0; j < 8; ++j)
                acc[j] += (float)f0[j] + m1 * (float)f1[j] + m2 * (float)f2[j] + m3 * (float)f3[j];
        }
        f16x8 o;
        if (valid) {
            float di = dinv[node];
#pragma unroll
            for (int j = 0; j < 8; ++j) {
                float v = acc[j] * di + bb[j];
                o[j] = (f16)(v > 0.f ? v : 0.f);
            }
        } else {
#pragma unroll
            for (int j = 0; j < 8; ++j) o[j] = (f16)0.f;
        }
        *(f16x8*)&zT[nodeLocal * ZSTR + 8 * s] = o;
    }
    __syncthreads();

    // Phase 2: wave wv -> m-tile wv (nodes nodeBase+16*wv .. +15)
    int q = L >> 4, m = L & 15;
    const f16x8* w2f8 = (const f16x8*)w2f;
    f32x4 acc2[3] = {};
#pragma unroll
    for (int ks = 0; ks < 2; ++ks) {
        f16x8 afrag = *(const f16x8*)&zT[(16 * wv + m) * ZSTR + 32 * ks + 8 * q];
#pragma unroll
        for (int c = 0; c < 3; ++c)
            acc2[c] = __builtin_amdgcn_mfma_f32_16x16x32_f16(afrag, w2f8[(ks * 3 + c) * 64 + L], acc2[c], 0, 0, 0);
    }
#pragma unroll
    for (int r = 0; r < 4; ++r) {
        int node = nodeBase + 16 * wv + q * 4 + r;
        if (node < N_NODES) {
            float di = dinv[node];
            h2p[(size_t)node * OUT_DIM + m]      = (f16)(acc2[0][r] * di);
            h2p[(size_t)node * OUT_DIM + 16 + m] = (f16)(acc2[1][r] * di);
            if (m < 8)
                h2p[(size_t)node * OUT_DIM + 32 + m] = (f16)(acc2[2][r] * di);
        }
    }
}

// agg2: 1 node per 8-lane group (lanes s<5 carry the 80B row as f16x8),
// 32 groups per block; unroll-4 with masked tail -> 32 rows in flight per wave.
__global__ __launch_bounds__(256) void agg2_kernel(const f16* __restrict__ h2p,
                                                   const int* __restrict__ csr,
                                                   const int* __restrict__ row_start,
                                                   const int* __restrict__ cnt,
                                                   const float* __restrict__ dinv,
                                                   const float* __restrict__ b2,
                                                   float* __restrict__ out) {
    int t = threadIdx.x;
    int node = blockIdx.x * 32 + (t >> 3);
    int s = t & 7;                        // f16x8 slot: dims 8s..8s+7 (active s<5)
    if (node >= N_NODES || s >= 5) return;
    const f16x8* h8 = (const f16x8*)h2p;  // row stride 5 (f16x8 units)
    float acc[8];
    {
        f16x8 sv = h8[(size_t)node * 5 + s];   // self loop
#pragma unroll
        for (int j = 0; j < 8; ++j) acc[j] = (float)sv[j];
    }
    int lim = cnt[node];
    const int* cp = csr + row_start[node];
    for (int k = 0; k < lim; k += 4) {
        int k1 = (k + 1 < lim) ? k + 1 : k;
        int k2 = (k + 2 < lim) ? k + 2 : k;
        int k3 = (k + 3 < lim) ? k + 3 : k;
        int i0 = cp[k], i1 = cp[k1], i2 = cp[k2], i3 = cp[k3];
        f16x8 f0 = h8[(size_t)i0 * 5 + s];
        f16x8 f1 = h8[(size_t)i1 * 5 + s];
        f16x8 f2 = h8[(size_t)i2 * 5 + s];
        f16x8 f3 = h8[(size_t)i3 * 5 + s];
        float m1 = (k + 1 < lim) ? 1.f : 0.f;
        float m2 = (k + 2 < lim) ? 1.f : 0.f;
        float m3 = (k + 3 < lim) ? 1.f : 0.f;
#pragma unroll
        for (int j = 0; j < 8; ++j)
            acc[j] += (float)f0[j] + m1 * (float)f1[j] + m2 * (float)f2[j] + m3 * (float)f3[j];
    }
    float di = dinv[node];
    float4 o0, o1;
    o0.x = acc[0] * di + b2[8 * s + 0];
    o0.y = acc[1] * di + b2[8 * s + 1];
    o0.z = acc[2] * di + b2[8 * s + 2];
    o0.w = acc[3] * di + b2[8 * s + 3];
    o1.x = acc[4] * di + b2[8 * s + 4];
    o1.y = acc[5] * di + b2[8 * s + 5];
    o1.z = acc[6] * di + b2[8 * s + 6];
    o1.w = acc[7] * di + b2[8 * s + 7];
    *(float4*)&out[(size_t)node * OUT_DIM + 8 * s] = o0;
    *(float4*)&out[(size_t)node * OUT_DIM + 8 * s + 4] = o1;
}

extern "C" void kernel_launch(void* const* d_in, const int* in_sizes, int n_in,
                              void* d_out, int out_size, void* d_ws, size_t ws_size,
                              hipStream_t stream) {
    const float* x  = (const float*)d_in[0];
    const int*   ei = (const int*)d_in[1];      // [2, E] int32
    const float* W1 = (const float*)d_in[2];
    const float* b1 = (const float*)d_in[3];
    const float* W2 = (const float*)d_in[4];
    const float* b2 = (const float*)d_in[5];
    float* out = (float*)d_out;

    const int* src = ei;
    const int* dst = ei + N_EDGES;

    int* wsi        = (int*)d_ws;
    int* hist       = wsi;
    int* base       = hist + N_BUCKETS * N_CHUNKS;
    int* bucketTotal= base + N_BUCKETS * N_CHUNKS;
    int* bucketBase = bucketTotal + 1024;
    int* row_start  = bucketBase + 1024;
    int* cnt        = row_start + NPAD;
    int* csr        = cnt + NPAD;
    int* stage      = csr + N_EDGES;
    float* dinv     = (float*)(stage + N_EDGES);
    f16*   h1p      = (f16*)(dinv + NPAD);
    f16*   h2p      = h1p + (size_t)N_NODES * HID_DIM;
    f16*   w1f      = h2p + (size_t)N_NODES * OUT_DIM;   // 8192 f16
    f16*   w2f      = w1f + 8192;                        // 3072 f16

    // D1: hist (transposed layout) + wfrag jobs
    hist_kernel<<<N_CHUNKS + 2, 256, 0, stream>>>(dst, hist, W1, W2, w1f, w2f);
    // D2: per-bucket chunk scans (coalesced row reads)
    scan_chunks_kernel<<<N_BUCKETS, 256, 0, stream>>>(hist, base, bucketTotal);
    // D3: bucket-total scan
    scan_buckets_kernel<<<1, 256, 0, stream>>>(bucketTotal, bucketBase);
    // D4: scatter into bucket-grouped stage
    scatter_kernel<<<N_CHUNKS, 256, 0, stream>>>(src, dst, base, bucketBase, stage);
    // D5: place -> csr/row_start/cnt/dinv
    place_kernel<<<N_BUCKETS, 256, 0, stream>>>(stage, bucketBase, csr, row_start, cnt, dinv);
    // D6-D8: gemm1 -> fused agg1+gemm2 -> agg2
    gemm1_kernel<<<(N_NODES + 63) / 64, 256, 0, stream>>>(x, w1f, dinv, h1p);
    agg1mm_kernel<<<(N_NODES + 63) / 64, 256, 0, stream>>>(h1p, csr, row_start, cnt, dinv, b1, w2f, h2p);
    agg2_kernel<<<(N_NODES + 31) / 32, 256, 0, stream>>>(h2p, csr, row_start, cnt, dinv, b2, out);
}